// Round 1
// baseline (912.983 us; speedup 1.0000x reference)
//
#include <hip/hip_runtime.h>
#include <math.h>

// Problem constants
#define B_   256
#define T_   16
#define A_   400
#define N_   8
#define D_   512
#define BT_  4096      // B*T
#define AN_  3200      // A*N
#define BA_  102400    // B*A
#define U_   0.0625f   // 1/T
#define V_   0.125f    // 1/N
#define INV_MEAN (1.0f/1638400.0f)   // 1/(BA*T)

#define RCP(x) __builtin_amdgcn_rcpf(x)

// ---------------- normalize rows of [nrows][512] ----------------
__global__ __launch_bounds__(256)
void norm_k(const float* __restrict__ src, float* __restrict__ dst, int nrows)
{
    int wid  = threadIdx.x >> 6;
    int lane = threadIdx.x & 63;
    int row  = blockIdx.x * 4 + wid;
    if (row >= nrows) return;
    const float* s = src + (size_t)row * 512;
    float4 x = *(const float4*)(s + lane * 4);
    float4 y = *(const float4*)(s + 256 + lane * 4);
    float ss = x.x*x.x + x.y*x.y + x.z*x.z + x.w*x.w
             + y.x*y.x + y.y*y.y + y.z*y.z + y.w*y.w;
    ss += __shfl_xor(ss, 1);  ss += __shfl_xor(ss, 2);  ss += __shfl_xor(ss, 4);
    ss += __shfl_xor(ss, 8);  ss += __shfl_xor(ss, 16); ss += __shfl_xor(ss, 32);
    float inv = rsqrtf(ss);
    float* d = dst + (size_t)row * 512;
    float4 ox, oy;
    ox.x = x.x*inv; ox.y = x.y*inv; ox.z = x.z*inv; ox.w = x.w*inv;
    oy.x = y.x*inv; oy.y = y.y*inv; oy.z = y.z*inv; oy.w = y.w*inv;
    *(float4*)(d + lane * 4)       = ox;
    *(float4*)(d + 256 + lane * 4) = oy;
}

// ---------------- pools: img_pool[b][d], dsum[a][d] = mean_n(dtn)+mean_n(dsn) ----------------
__global__ __launch_bounds__(256)
void pools_k(const float* __restrict__ imf_n, const float* __restrict__ dsn,
             const float* __restrict__ dtn, float* __restrict__ img_pool,
             float* __restrict__ dsum, int* __restrict__ ifound)
{
    int i = blockIdx.x * 256 + threadIdx.x;
    if (i == 0) { ifound[0] = 0; ifound[1] = 0; }
    if (i < 131072) {               // img_pool: (b,d)
        int b = i >> 9, d = i & 511;
        float s = 0.f;
        #pragma unroll
        for (int t = 0; t < 16; ++t) s += imf_n[((size_t)(b*16 + t))*512 + d];
        img_pool[i] = s * 0.0625f;
    } else if (i < 131072 + 204800) { // dsum: (a,d)
        int k = i - 131072;
        int a = k >> 9, d = k & 511;
        float s1 = 0.f, s2 = 0.f;
        #pragma unroll
        for (int n = 0; n < 8; ++n) {
            s1 += dtn[((size_t)(a*8 + n))*512 + d];
            s2 += dsn[((size_t)(a*8 + n))*512 + d];
        }
        dsum[k] = (s1 + s2) * 0.125f;
    }
}

// ---------------- pooled-logit base: out[b][a] = 0.5*ls*dot(img_pool[b], dsum[a]) ----------------
__global__ __launch_bounds__(256)
void base_k(const float* __restrict__ img_pool, const float* __restrict__ dsum,
            const float* __restrict__ lsc, float* __restrict__ out)
{
    int wid  = threadIdx.x >> 6;
    int lane = threadIdx.x & 63;
    int wg   = blockIdx.x * 4 + wid;   // 0..12799 = b*50 + ac
    int b  = wg / 50;
    int ac = wg % 50;
    int ai = lane >> 3, dg = lane & 7;
    int a  = ac * 8 + ai;
    const float* ip = img_pool + (size_t)b * 512 + dg * 64;
    const float* dp = dsum + (size_t)a * 512 + dg * 64;
    float s = 0.f;
    #pragma unroll
    for (int k = 0; k < 64; k += 4) {
        float4 x = *(const float4*)(ip + k);
        float4 y = *(const float4*)(dp + k);
        s = fmaf(x.x, y.x, s); s = fmaf(x.y, y.y, s);
        s = fmaf(x.z, y.z, s); s = fmaf(x.w, y.w, s);
    }
    s += __shfl_xor(s, 1); s += __shfl_xor(s, 2); s += __shfl_xor(s, 4);
    if (dg == 0) {
        float ls = __expf(lsc[0]);
        out[(size_t)b * 400 + a] = 0.5f * ls * s;
    }
}

// ---------------- GEMM: sim[b][a][t][n] = imf_n[bt] . dnorm[an]  (fp32 VALU) ----------------
__global__ __launch_bounds__(256)
void gemm_sim(const float* __restrict__ Amat, const float* __restrict__ Bmat,
              float* __restrict__ C)
{
    __shared__ float As[16][64];
    __shared__ float Bs[16][64];
    int tid = threadIdx.x;
    int bx = blockIdx.x % 50;        // col tile (AN/64)
    int by = blockIdx.x / 50;        // row tile (BT/64)
    int m0 = by * 64, c0 = bx * 64;
    int ty = tid >> 4, tx = tid & 15;
    int lr = tid >> 2;               // 0..63
    int lk = (tid & 3) << 2;         // 0,4,8,12
    float acc[4][4];
    #pragma unroll
    for (int i = 0; i < 4; ++i)
        #pragma unroll
        for (int jj = 0; jj < 4; ++jj) acc[i][jj] = 0.f;
    const float* Aptr = Amat + (size_t)(m0 + lr) * 512 + lk;
    const float* Bptr = Bmat + (size_t)(c0 + lr) * 512 + lk;
    for (int k0 = 0; k0 < 512; k0 += 16) {
        float4 av = *(const float4*)(Aptr + k0);
        float4 bv = *(const float4*)(Bptr + k0);
        __syncthreads();
        As[lk+0][lr] = av.x; As[lk+1][lr] = av.y; As[lk+2][lr] = av.z; As[lk+3][lr] = av.w;
        Bs[lk+0][lr] = bv.x; Bs[lk+1][lr] = bv.y; Bs[lk+2][lr] = bv.z; Bs[lk+3][lr] = bv.w;
        __syncthreads();
        #pragma unroll
        for (int kk = 0; kk < 16; ++kk) {
            float4 a = *(const float4*)&As[kk][ty << 2];
            float4 b = *(const float4*)&Bs[kk][tx << 2];
            float aa[4] = {a.x, a.y, a.z, a.w};
            float bb[4] = {b.x, b.y, b.z, b.w};
            #pragma unroll
            for (int i = 0; i < 4; ++i)
                #pragma unroll
                for (int jj = 0; jj < 4; ++jj)
                    acc[i][jj] = fmaf(aa[i], bb[jj], acc[i][jj]);
        }
    }
    int ncol = c0 + (tx << 2);
    int a_idx = ncol >> 3, nlo = ncol & 7;   // nlo in {0,4}
    #pragma unroll
    for (int i = 0; i < 4; ++i) {
        int m = m0 + (ty << 2) + i;
        int b_idx = m >> 4, t_idx = m & 15;
        float4 v = make_float4(acc[i][0], acc[i][1], acc[i][2], acc[i][3]);
        *(float4*)&C[(((size_t)b_idx * 400 + a_idx) * 16 + t_idx) * 8 + nlo] = v;
    }
}

// ---------------- Sinkhorn stage: bodies (it0, it1], record per-iter err partials ----------------
// sim: [BA][16][8]; errs: [100][6400]; ckc: [6][BA][8] (c after bodies 16..96);
// ckr: [2][BA][16] (r after bodies 16, 48)
__global__ __launch_bounds__(256)
void sink_stage(const float* __restrict__ sim, float* __restrict__ errs,
                float* __restrict__ ckc, float* __restrict__ ckr,
                const int* __restrict__ fnd, int it0, int it1)
{
    if (it0 > 0 && *fnd) return;
    __shared__ float eacc[52][16];
    int tid  = threadIdx.x;
    int lane = tid & 63, wid = tid >> 6;
    int j = lane >> 4, t = lane & 15;
    int p = (blockIdx.x * 4 + wid) * 4 + j;
    const float* sp = sim + (size_t)p * 128 + t * 8;
    float4 sa = *(const float4*)sp;
    float4 sb = *(const float4*)(sp + 4);
    float K[8];
    K[0] = __expf((sa.x - 1.f) * 10.f); K[1] = __expf((sa.y - 1.f) * 10.f);
    K[2] = __expf((sa.z - 1.f) * 10.f); K[3] = __expf((sa.w - 1.f) * 10.f);
    K[4] = __expf((sb.x - 1.f) * 10.f); K[5] = __expf((sb.y - 1.f) * 10.f);
    K[6] = __expf((sb.z - 1.f) * 10.f); K[7] = __expf((sb.w - 1.f) * 10.f);
    float c[8];
    float rp;
    if (it0 > 0) {
        const float* cp = ckc + ((size_t)(it0/16 - 1) * BA_ + p) * 8;
        float4 ca = *(const float4*)cp;
        float4 cb = *(const float4*)(cp + 4);
        c[0]=ca.x; c[1]=ca.y; c[2]=ca.z; c[3]=ca.w;
        c[4]=cb.x; c[5]=cb.y; c[6]=cb.z; c[7]=cb.w;
        int rslot = (it0 == 16) ? 0 : 1;
        rp = ckr[(size_t)rslot * (BA_*16) + (size_t)p * 16 + t];
    } else {
        #pragma unroll
        for (int n = 0; n < 8; ++n) c[n] = 1.f;
        rp = 1.f;
    }
    for (int idx = it0; idx < it1; ++idx) {
        float s = 0.f;
        #pragma unroll
        for (int n = 0; n < 8; ++n) s = fmaf(K[n], c[n], s);
        float r = U_ * RCP(s);
        float d = fabsf(r - rp);
        rp = r;
        d += __shfl_xor(d, 1); d += __shfl_xor(d, 2);
        d += __shfl_xor(d, 4); d += __shfl_xor(d, 8);
        if (t == 0) eacc[idx - it0][(wid << 2) | j] = d;
        float q[8];
        #pragma unroll
        for (int n = 0; n < 8; ++n) q[n] = K[n] * r;
        #pragma unroll
        for (int n = 0; n < 8; ++n) {
            q[n] += __shfl_xor(q[n], 1); q[n] += __shfl_xor(q[n], 2);
            q[n] += __shfl_xor(q[n], 4); q[n] += __shfl_xor(q[n], 8);
        }
        #pragma unroll
        for (int n = 0; n < 8; ++n) c[n] = V_ * RCP(q[n]);
        if ((idx & 15) == 15) {
            if (t == 0 && idx < 96) {
                float* cp = ckc + ((size_t)(idx >> 4) * BA_ + p) * 8;
                *(float4*)cp       = make_float4(c[0], c[1], c[2], c[3]);
                *(float4*)(cp + 4) = make_float4(c[4], c[5], c[6], c[7]);
            }
            if (idx == 15 || idx == 47) {
                int rslot = (idx == 15) ? 0 : 1;
                ckr[(size_t)rslot * (BA_*16) + (size_t)p * 16 + t] = rp;
            }
        }
    }
    __syncthreads();
    int range = it1 - it0;
    if (tid < range) {
        float s = 0.f;
        #pragma unroll
        for (int k = 0; k < 16; ++k) s += eacc[tid][k];
        errs[(size_t)(it0 + tid) * 6400 + blockIdx.x] = s;
    }
}

// ---------------- per-iteration err sums over blocks ----------------
__global__ __launch_bounds__(256)
void red_k(const float* __restrict__ errs, float* __restrict__ err_iter,
           const int* __restrict__ fnd, int it0)
{
    if (it0 > 0 && *fnd) return;
    int idx = it0 + blockIdx.x;
    const float* e = errs + (size_t)idx * 6400;
    float s = 0.f;
    for (int k = threadIdx.x; k < 6400; k += 256) s += e[k];
    s += __shfl_xor(s, 1);  s += __shfl_xor(s, 2);  s += __shfl_xor(s, 4);
    s += __shfl_xor(s, 8);  s += __shfl_xor(s, 16); s += __shfl_xor(s, 32);
    __shared__ float red[4];
    int wid = threadIdx.x >> 6;
    if ((threadIdx.x & 63) == 0) red[wid] = s;
    __syncthreads();
    if (threadIdx.x == 0) err_iter[idx] = red[0] + red[1] + red[2] + red[3];
}

// ---------------- scan for first converged iteration ----------------
__global__ void fin_k(const float* __restrict__ err_iter, int* __restrict__ iters,
                      int* __restrict__ fnd, int it0, int it1, int is_final)
{
    if (threadIdx.x != 0 || blockIdx.x != 0) return;
    if (*fnd) return;
    for (int idx = it0; idx < it1; ++idx) {
        if (err_iter[idx] * INV_MEAN < 0.01f) {
            *iters = idx + 1;
            *fnd = 1;
            return;
        }
    }
    if (is_final) *iters = 100;
}

// ---------------- final pass: resume from checkpoint, compute score = sum P*sim ----------------
__global__ __launch_bounds__(256)
void sink_final(const float* __restrict__ sim, const float* __restrict__ ckc,
                const int* __restrict__ itr, float* __restrict__ score)
{
    int I = *itr;
    int i0 = ((I - 1) >> 4) << 4;
    int tid  = threadIdx.x;
    int lane = tid & 63, wid = tid >> 6;
    int j = lane >> 4, t = lane & 15;
    int p = (blockIdx.x * 4 + wid) * 4 + j;
    const float* sp = sim + (size_t)p * 128 + t * 8;
    float4 sa = *(const float4*)sp;
    float4 sb = *(const float4*)(sp + 4);
    float K[8];
    K[0] = __expf((sa.x - 1.f) * 10.f); K[1] = __expf((sa.y - 1.f) * 10.f);
    K[2] = __expf((sa.z - 1.f) * 10.f); K[3] = __expf((sa.w - 1.f) * 10.f);
    K[4] = __expf((sb.x - 1.f) * 10.f); K[5] = __expf((sb.y - 1.f) * 10.f);
    K[6] = __expf((sb.z - 1.f) * 10.f); K[7] = __expf((sb.w - 1.f) * 10.f);
    float c[8];
    if (i0 > 0) {
        const float* cp = ckc + ((size_t)((i0 >> 4) - 1) * BA_ + p) * 8;
        float4 ca = *(const float4*)cp;
        float4 cb = *(const float4*)(cp + 4);
        c[0]=ca.x; c[1]=ca.y; c[2]=ca.z; c[3]=ca.w;
        c[4]=cb.x; c[5]=cb.y; c[6]=cb.z; c[7]=cb.w;
    } else {
        #pragma unroll
        for (int n = 0; n < 8; ++n) c[n] = 1.f;
    }
    float r = 0.f;
    for (int idx = i0; idx < I; ++idx) {
        float s = 0.f;
        #pragma unroll
        for (int n = 0; n < 8; ++n) s = fmaf(K[n], c[n], s);
        r = U_ * RCP(s);
        float q[8];
        #pragma unroll
        for (int n = 0; n < 8; ++n) q[n] = K[n] * r;
        #pragma unroll
        for (int n = 0; n < 8; ++n) {
            q[n] += __shfl_xor(q[n], 1); q[n] += __shfl_xor(q[n], 2);
            q[n] += __shfl_xor(q[n], 4); q[n] += __shfl_xor(q[n], 8);
        }
        #pragma unroll
        for (int n = 0; n < 8; ++n) c[n] = V_ * RCP(q[n]);
    }
    float sv[8] = {sa.x, sa.y, sa.z, sa.w, sb.x, sb.y, sb.z, sb.w};
    float g = 0.f;
    #pragma unroll
    for (int n = 0; n < 8; ++n) g = fmaf(K[n] * c[n], sv[n], g);
    float part = r * g;
    part += __shfl_xor(part, 1); part += __shfl_xor(part, 2);
    part += __shfl_xor(part, 4); part += __shfl_xor(part, 8);
    if (t == 0) score[p] = part;
}

// ---------------- final combine ----------------
__global__ __launch_bounds__(256)
void finalize_k(const float* __restrict__ st, const float* __restrict__ ss,
                const float* __restrict__ lsc, float* __restrict__ out)
{
    int i = blockIdx.x * 256 + threadIdx.x;
    float ls = __expf(lsc[0]);
    out[i] += 0.5f * ls * (st[i] + ss[i]);
}

extern "C" void kernel_launch(void* const* d_in, const int* in_sizes, int n_in,
                              void* d_out, int out_size, void* d_ws, size_t ws_size,
                              hipStream_t stream)
{
    (void)in_sizes; (void)n_in; (void)out_size; (void)ws_size;
    const float* imf = (const float*)d_in[0];
    const float* ds  = (const float*)d_in[1];   // spatial
    const float* dt  = (const float*)d_in[2];   // temporal
    const float* lsc = (const float*)d_in[3];
    float* out = (float*)d_out;

    float* imf_n    = (float*)d_ws;             // 2,097,152
    float* dsn      = imf_n + 2097152;          // 1,638,400
    float* dtn      = dsn + 1638400;            // 1,638,400
    float* img_pool = dtn + 1638400;            // 131,072
    float* dsum     = img_pool + 131072;        // 204,800
    float* sim      = dsum + 204800;            // 13,107,200 (shared between sets)
    float* errs     = sim + 13107200;           // 640,000
    float* err_iter = errs + 640000;            // 128
    float* ckc      = err_iter + 128;           // 4,915,200
    float* ckr      = ckc + 4915200;            // 3,276,800
    float* score_t  = ckr + 3276800;            // 102,400
    float* score_s  = score_t + 102400;         // 102,400
    int*   ifound   = (int*)(score_s + 102400); // found[2], iters[2]

    norm_k<<<1024, 256, 0, stream>>>(imf, imf_n, 4096);
    norm_k<<<800, 256, 0, stream>>>(ds, dsn, 3200);
    norm_k<<<800, 256, 0, stream>>>(dt, dtn, 3200);
    pools_k<<<1312, 256, 0, stream>>>(imf_n, dsn, dtn, img_pool, dsum, ifound);
    base_k<<<3200, 256, 0, stream>>>(img_pool, dsum, lsc, out);

    for (int set = 0; set < 2; ++set) {
        const float* dnorm = (set == 0) ? dtn : dsn;   // temporal first
        float* score = (set == 0) ? score_t : score_s;
        int* fnd = ifound + set;
        int* itr = ifound + 2 + set;
        gemm_sim<<<3200, 256, 0, stream>>>(imf_n, dnorm, sim);
        sink_stage<<<6400, 256, 0, stream>>>(sim, errs, ckc, ckr, fnd, 0, 16);
        red_k<<<16, 256, 0, stream>>>(errs, err_iter, fnd, 0);
        fin_k<<<1, 64, 0, stream>>>(err_iter, itr, fnd, 0, 16, 0);
        sink_stage<<<6400, 256, 0, stream>>>(sim, errs, ckc, ckr, fnd, 16, 48);
        red_k<<<32, 256, 0, stream>>>(errs, err_iter, fnd, 16);
        fin_k<<<1, 64, 0, stream>>>(err_iter, itr, fnd, 16, 48, 0);
        sink_stage<<<6400, 256, 0, stream>>>(sim, errs, ckc, ckr, fnd, 48, 100);
        red_k<<<52, 256, 0, stream>>>(errs, err_iter, fnd, 48);
        fin_k<<<1, 64, 0, stream>>>(err_iter, itr, fnd, 48, 100, 1);
        sink_final<<<6400, 256, 0, stream>>>(sim, ckc, itr, score);
    }

    finalize_k<<<400, 256, 0, stream>>>(score_t, score_s, lsc, out);
}

// Round 2
// 534.743 us; speedup vs baseline: 1.7073x; 1.7073x over previous
//
#include <hip/hip_runtime.h>
#include <math.h>

typedef unsigned short u16;
typedef unsigned int   u32;
typedef __attribute__((ext_vector_type(8))) short short8;
typedef __attribute__((ext_vector_type(4))) float f32x4;

// Problem constants
#define B_   256
#define T_   16
#define A_   400
#define N_   8
#define D_   512
#define BT_  4096      // B*T
#define AN_  3200      // A*N
#define BA_  102400    // B*A
#define U_   0.0625f   // 1/T
#define V_   0.125f    // 1/N
#define INV_MEAN (1.0f/1638400.0f)   // 1/(BA*T)

#define RCP(x) __builtin_amdgcn_rcpf(x)

__device__ __forceinline__ u16 f2bf(float x) {
    u32 u = __float_as_uint(x);
    u32 r = (u + 0x7fffu + ((u >> 16) & 1u)) >> 16;
    return (u16)r;
}
__device__ __forceinline__ float bf2f(u16 h) {
    return __uint_as_float(((u32)h) << 16);
}

__device__ __forceinline__ void gl_lds16(const u16* g, void* l) {
    __builtin_amdgcn_global_load_lds(
        (const __attribute__((address_space(1))) void*)g,
        (__attribute__((address_space(3))) void*)l, 16, 0, 0);
}

// conditional-XOR permutation network: a[i] <- a[i ^ m], m = s0 + 2*s1 + 4*s2
#define CSWP(cond, x, y) { float _tx = (x), _ty = (y); (x) = (cond) ? _ty : _tx; (y) = (cond) ? _tx : _ty; }
__device__ __forceinline__ void perm8(float* a, bool s0, bool s1, bool s2) {
    CSWP(s0, a[0], a[1]); CSWP(s0, a[2], a[3]); CSWP(s0, a[4], a[5]); CSWP(s0, a[6], a[7]);
    CSWP(s1, a[0], a[2]); CSWP(s1, a[1], a[3]); CSWP(s1, a[4], a[6]); CSWP(s1, a[5], a[7]);
    CSWP(s2, a[0], a[4]); CSWP(s2, a[1], a[5]); CSWP(s2, a[2], a[6]); CSWP(s2, a[3], a[7]);
}

// ---------------- normalize rows of [nrows][512] + bf16 hi/lo split ----------------
__global__ __launch_bounds__(256)
void norm_k(const float* __restrict__ src, float* __restrict__ dst,
            u16* __restrict__ hi, u16* __restrict__ lo, int nrows)
{
    int wid  = threadIdx.x >> 6;
    int lane = threadIdx.x & 63;
    int row  = blockIdx.x * 4 + wid;
    if (row >= nrows) return;
    const float* s = src + (size_t)row * 512;
    float4 x = *(const float4*)(s + lane * 4);
    float4 y = *(const float4*)(s + 256 + lane * 4);
    float ss = x.x*x.x + x.y*x.y + x.z*x.z + x.w*x.w
             + y.x*y.x + y.y*y.y + y.z*y.z + y.w*y.w;
    ss += __shfl_xor(ss, 1);  ss += __shfl_xor(ss, 2);  ss += __shfl_xor(ss, 4);
    ss += __shfl_xor(ss, 8);  ss += __shfl_xor(ss, 16); ss += __shfl_xor(ss, 32);
    float inv = rsqrtf(ss);
    float v0[4] = {x.x*inv, x.y*inv, x.z*inv, x.w*inv};
    float v1[4] = {y.x*inv, y.y*inv, y.z*inv, y.w*inv};
    float* d = dst + (size_t)row * 512;
    *(float4*)(d + lane * 4)       = make_float4(v0[0], v0[1], v0[2], v0[3]);
    *(float4*)(d + 256 + lane * 4) = make_float4(v1[0], v1[1], v1[2], v1[3]);
    ushort4 h0, h1, l0, l1;
    u16* hp = (u16*)&h0; u16* lp = (u16*)&l0;
    #pragma unroll
    for (int k = 0; k < 4; ++k) { hp[k] = f2bf(v0[k]); lp[k] = f2bf(v0[k] - bf2f(hp[k])); }
    hp = (u16*)&h1; lp = (u16*)&l1;
    #pragma unroll
    for (int k = 0; k < 4; ++k) { hp[k] = f2bf(v1[k]); lp[k] = f2bf(v1[k] - bf2f(hp[k])); }
    *(ushort4*)(hi + (size_t)row * 512 + lane * 4)       = h0;
    *(ushort4*)(hi + (size_t)row * 512 + 256 + lane * 4) = h1;
    *(ushort4*)(lo + (size_t)row * 512 + lane * 4)       = l0;
    *(ushort4*)(lo + (size_t)row * 512 + 256 + lane * 4) = l1;
}

// ---------------- pools ----------------
__global__ __launch_bounds__(256)
void pools_k(const float* __restrict__ imf_n, const float* __restrict__ dsn,
             const float* __restrict__ dtn, float* __restrict__ img_pool,
             float* __restrict__ dsum, int* __restrict__ ifound)
{
    int i = blockIdx.x * 256 + threadIdx.x;
    if (i == 0) { ifound[0] = 0; ifound[1] = 0; }
    if (i < 131072) {               // img_pool: (b,d)
        int b = i >> 9, d = i & 511;
        float s = 0.f;
        #pragma unroll
        for (int t = 0; t < 16; ++t) s += imf_n[((size_t)(b*16 + t))*512 + d];
        img_pool[i] = s * 0.0625f;
    } else if (i < 131072 + 204800) { // dsum: (a,d)
        int k = i - 131072;
        int a = k >> 9, d = k & 511;
        float s1 = 0.f, s2 = 0.f;
        #pragma unroll
        for (int n = 0; n < 8; ++n) {
            s1 += dtn[((size_t)(a*8 + n))*512 + d];
            s2 += dsn[((size_t)(a*8 + n))*512 + d];
        }
        dsum[k] = (s1 + s2) * 0.125f;
    }
}

// ---------------- pooled-logit base ----------------
__global__ __launch_bounds__(256)
void base_k(const float* __restrict__ img_pool, const float* __restrict__ dsum,
            const float* __restrict__ lsc, float* __restrict__ out)
{
    int wid  = threadIdx.x >> 6;
    int lane = threadIdx.x & 63;
    int wg   = blockIdx.x * 4 + wid;
    int b  = wg / 50;
    int ac = wg % 50;
    int ai = lane >> 3, dg = lane & 7;
    int a  = ac * 8 + ai;
    const float* ip = img_pool + (size_t)b * 512 + dg * 64;
    const float* dp = dsum + (size_t)a * 512 + dg * 64;
    float s = 0.f;
    #pragma unroll
    for (int k = 0; k < 64; k += 4) {
        float4 x = *(const float4*)(ip + k);
        float4 y = *(const float4*)(dp + k);
        s = fmaf(x.x, y.x, s); s = fmaf(x.y, y.y, s);
        s = fmaf(x.z, y.z, s); s = fmaf(x.w, y.w, s);
    }
    s += __shfl_xor(s, 1); s += __shfl_xor(s, 2); s += __shfl_xor(s, 4);
    if (dg == 0) {
        float ls = __expf(lsc[0]);
        out[(size_t)b * 400 + a] = 0.5f * ls * s;
    }
}

// ---------------- bf16x3-split MFMA GEMM: C[m][n] = A[m] . B[n]  (both K-major) ----------------
// A: 4096x512 (hi/lo bf16), B: 3200x512 (hi/lo bf16), C scattered as sim[b][a][t][n]
__global__ __launch_bounds__(256)
void gemm_mfma(const u16* __restrict__ Ahi, const u16* __restrict__ Alo,
               const u16* __restrict__ Bhi, const u16* __restrict__ Blo,
               float* __restrict__ C)
{
    __shared__ u16 sm[4][128 * 32];   // Ahi, Alo, Bhi, Blo tiles (8KB each, linear)
    int bid = blockIdx.x;
    int swz = (bid & 7) * 100 + (bid >> 3);     // 800 % 8 == 0: bijective XCD swizzle
    int by = swz / 25, bx = swz % 25;
    int m0 = by * 128, n0 = bx * 128;
    int tid = threadIdx.x, lane = tid & 63, w = tid >> 6;
    int wr = w >> 1, wc = w & 1;
    int srow = tid >> 2, sc = tid & 3;

    f32x4 acc[4][4];
    #pragma unroll
    for (int i = 0; i < 4; ++i)
        #pragma unroll
        for (int jj = 0; jj < 4; ++jj) acc[i][jj] = (f32x4)0.f;

    for (int k0 = 0; k0 < 512; k0 += 32) {
        __syncthreads();
        #pragma unroll
        for (int q = 0; q < 2; ++q) {
            int row = q * 64 + srow;
            int gch = sc ^ ((row >> 2) & 3);   // pre-swizzled global source (rule 21)
            size_t goffA = (size_t)(m0 + row) * 512 + k0 + gch * 8;
            size_t goffB = (size_t)(n0 + row) * 512 + k0 + gch * 8;
            u32 ldso = (u32)(q * 4096 + w * 1024);
            gl_lds16(Ahi + goffA, (char*)sm[0] + ldso);
            gl_lds16(Alo + goffA, (char*)sm[1] + ldso);
            gl_lds16(Bhi + goffB, (char*)sm[2] + ldso);
            gl_lds16(Blo + goffB, (char*)sm[3] + ldso);
        }
        __syncthreads();
        int lr = lane & 15, kg = lane >> 4;
        short8 ah[4], al[4], bh[4], bl[4];
        #pragma unroll
        for (int i = 0; i < 4; ++i) {
            int ar = wr * 64 + i * 16 + lr;
            u32 offa = (u32)(ar * 64 + (kg ^ ((ar >> 2) & 3)) * 16);
            ah[i] = *(const short8*)((const char*)sm[0] + offa);
            al[i] = *(const short8*)((const char*)sm[1] + offa);
            int br = wc * 64 + i * 16 + lr;
            u32 offb = (u32)(br * 64 + (kg ^ ((br >> 2) & 3)) * 16);
            bh[i] = *(const short8*)((const char*)sm[2] + offb);
            bl[i] = *(const short8*)((const char*)sm[3] + offb);
        }
        #pragma unroll
        for (int i = 0; i < 4; ++i)
            #pragma unroll
            for (int jj = 0; jj < 4; ++jj) {
                acc[i][jj] = __builtin_amdgcn_mfma_f32_16x16x32_bf16(ah[i], bh[jj], acc[i][jj], 0, 0, 0);
                acc[i][jj] = __builtin_amdgcn_mfma_f32_16x16x32_bf16(ah[i], bl[jj], acc[i][jj], 0, 0, 0);
                acc[i][jj] = __builtin_amdgcn_mfma_f32_16x16x32_bf16(al[i], bh[jj], acc[i][jj], 0, 0, 0);
            }
    }
    // epilogue: C[((b*400+a)*16+t)*8+n]
    int lr = lane & 15, hi4 = (lane >> 4) * 4;
    #pragma unroll
    for (int i = 0; i < 4; ++i) {
        int m_base = m0 + wr * 64 + i * 16;         // multiple of 16
        int bi = m_base >> 4;
        #pragma unroll
        for (int jj = 0; jj < 4; ++jj) {
            int colg = n0 + wc * 64 + jj * 16 + lr;
            int ai = colg >> 3, nn = colg & 7;
            size_t base = (((size_t)bi * 400 + ai) * 16) * 8 + nn;
            #pragma unroll
            for (int rr = 0; rr < 4; ++rr)
                C[base + (size_t)(hi4 + rr) * 8] = acc[i][jj][rr];
        }
    }
}

// ---------------- Sinkhorn stage ----------------
// sim: [BA][16][8]; errs: [100][6400]; ckc: [6][BA][8]; ckr: [2][BA][16]
__global__ __launch_bounds__(256)
void sink_stage(const float* __restrict__ sim, float* __restrict__ errs,
                float* __restrict__ ckc, float* __restrict__ ckr,
                const int* __restrict__ fnd, int it0, int it1)
{
    if (it0 > 0 && *fnd) return;
    __shared__ float eacc[52][16];
    int tid  = threadIdx.x;
    int lane = tid & 63, wid = tid >> 6;
    int j = lane >> 4, t = lane & 15;
    int p = (blockIdx.x * 4 + wid) * 4 + j;
    const float* sp = sim + (size_t)p * 128 + t * 8;
    float4 sa = *(const float4*)sp;
    float4 sb = *(const float4*)(sp + 4);
    float K[8] = {sa.x, sa.y, sa.z, sa.w, sb.x, sb.y, sb.z, sb.w};
    #pragma unroll
    for (int n = 0; n < 8; ++n) K[n] = __expf((K[n] - 1.f) * 10.f);
    bool s0 = (t & 2) != 0, s1 = (t & 4) != 0, s2 = (t & 8) != 0;
    perm8(K, s0, s1, s2);   // K[i] = K_nat[n_own ^ i], n_own = (t>>1)&7
    float c[8];
    float rp;
    if (it0 > 0) {
        const float* cp = ckc + ((size_t)(it0/16 - 1) * BA_ + p) * 8;
        float4 ca = *(const float4*)cp;
        float4 cb = *(const float4*)(cp + 4);
        c[0]=ca.x; c[1]=ca.y; c[2]=ca.z; c[3]=ca.w;
        c[4]=cb.x; c[5]=cb.y; c[6]=cb.z; c[7]=cb.w;
        perm8(c, s0, s1, s2);
        int rslot = (it0 == 16) ? 0 : 1;
        rp = ckr[(size_t)rslot * (BA_*16) + (size_t)p * 16 + t];
    } else {
        #pragma unroll
        for (int n = 0; n < 8; ++n) c[n] = 1.f;
        rp = 1.f;
    }
    for (int idx = it0; idx < it1; ++idx) {
        float s = 0.f;
        #pragma unroll
        for (int n = 0; n < 8; ++n) s = fmaf(K[n], c[n], s);
        float r = U_ * RCP(s);
        float d = fabsf(r - rp);
        rp = r;
        d += __shfl_xor(d, 1); d += __shfl_xor(d, 2);
        d += __shfl_xor(d, 4); d += __shfl_xor(d, 8);
        if (t == 0) eacc[idx - it0][(wid << 2) | j] = d;
        float q[8];
        #pragma unroll
        for (int n = 0; n < 8; ++n) q[n] = K[n] * r;
        // reduce-scatter (compile-time indices in permuted coords)
        q[0] += __shfl_xor(q[4], 8); q[1] += __shfl_xor(q[5], 8);
        q[2] += __shfl_xor(q[6], 8); q[3] += __shfl_xor(q[7], 8);
        q[0] += __shfl_xor(q[2], 4); q[1] += __shfl_xor(q[3], 4);
        q[0] += __shfl_xor(q[1], 2);
        q[0] += __shfl_xor(q[0], 1);
        c[0] = V_ * RCP(q[0]);
        // all-gather
        c[1] = __shfl_xor(c[0], 2);
        c[2] = __shfl_xor(c[0], 4); c[3] = __shfl_xor(c[1], 4);
        c[4] = __shfl_xor(c[0], 8); c[5] = __shfl_xor(c[1], 8);
        c[6] = __shfl_xor(c[2], 8); c[7] = __shfl_xor(c[3], 8);
        if ((idx & 15) == 15) {
            if (t == 0 && idx < 96) {   // t==0 has natural order
                float* cp = ckc + ((size_t)(idx >> 4) * BA_ + p) * 8;
                *(float4*)cp       = make_float4(c[0], c[1], c[2], c[3]);
                *(float4*)(cp + 4) = make_float4(c[4], c[5], c[6], c[7]);
            }
            if (idx == 15 || idx == 47) {
                int rslot = (idx == 15) ? 0 : 1;
                ckr[(size_t)rslot * (BA_*16) + (size_t)p * 16 + t] = rp;
            }
        }
    }
    __syncthreads();
    int range = it1 - it0;
    if (tid < range) {
        float s = 0.f;
        #pragma unroll
        for (int k = 0; k < 16; ++k) s += eacc[tid][k];
        errs[(size_t)(it0 + tid) * 6400 + blockIdx.x] = s;
    }
}

// ---------------- per-iteration err sums over blocks ----------------
__global__ __launch_bounds__(256)
void red_k(const float* __restrict__ errs, float* __restrict__ err_iter,
           const int* __restrict__ fnd, int it0)
{
    if (it0 > 0 && *fnd) return;
    int idx = it0 + blockIdx.x;
    const float* e = errs + (size_t)idx * 6400;
    float s = 0.f;
    for (int k = threadIdx.x; k < 6400; k += 256) s += e[k];
    s += __shfl_xor(s, 1);  s += __shfl_xor(s, 2);  s += __shfl_xor(s, 4);
    s += __shfl_xor(s, 8);  s += __shfl_xor(s, 16); s += __shfl_xor(s, 32);
    __shared__ float red[4];
    int wid = threadIdx.x >> 6;
    if ((threadIdx.x & 63) == 0) red[wid] = s;
    __syncthreads();
    if (threadIdx.x == 0) err_iter[idx] = red[0] + red[1] + red[2] + red[3];
}

// ---------------- scan for first converged iteration ----------------
__global__ void fin_k(const float* __restrict__ err_iter, int* __restrict__ iters,
                      int* __restrict__ fnd, int it0, int it1, int is_final)
{
    if (threadIdx.x != 0 || blockIdx.x != 0) return;
    if (*fnd) return;
    for (int idx = it0; idx < it1; ++idx) {
        if (err_iter[idx] * INV_MEAN < 0.01f) {
            *iters = idx + 1;
            *fnd = 1;
            return;
        }
    }
    if (is_final) *iters = 100;
}

// ---------------- final pass: resume from checkpoint, score = sum P*sim ----------------
__global__ __launch_bounds__(256)
void sink_final(const float* __restrict__ sim, const float* __restrict__ ckc,
                const int* __restrict__ itr, float* __restrict__ score)
{
    int I = *itr;
    int i0 = ((I - 1) >> 4) << 4;
    int tid  = threadIdx.x;
    int lane = tid & 63, wid = tid >> 6;
    int j = lane >> 4, t = lane & 15;
    int p = (blockIdx.x * 4 + wid) * 4 + j;
    const float* sp = sim + (size_t)p * 128 + t * 8;
    float4 sa = *(const float4*)sp;
    float4 sb = *(const float4*)(sp + 4);
    float sv[8] = {sa.x, sa.y, sa.z, sa.w, sb.x, sb.y, sb.z, sb.w};
    float K[8];
    #pragma unroll
    for (int n = 0; n < 8; ++n) K[n] = __expf((sv[n] - 1.f) * 10.f);
    bool s0 = (t & 2) != 0, s1 = (t & 4) != 0, s2 = (t & 8) != 0;
    perm8(K, s0, s1, s2);
    perm8(sv, s0, s1, s2);
    float c[8];
    if (i0 > 0) {
        const float* cp = ckc + ((size_t)((i0 >> 4) - 1) * BA_ + p) * 8;
        float4 ca = *(const float4*)cp;
        float4 cb = *(const float4*)(cp + 4);
        c[0]=ca.x; c[1]=ca.y; c[2]=ca.z; c[3]=ca.w;
        c[4]=cb.x; c[5]=cb.y; c[6]=cb.z; c[7]=cb.w;
        perm8(c, s0, s1, s2);
    } else {
        #pragma unroll
        for (int n = 0; n < 8; ++n) c[n] = 1.f;
    }
    float r = 0.f;
    for (int idx = i0; idx < I; ++idx) {
        float s = 0.f;
        #pragma unroll
        for (int n = 0; n < 8; ++n) s = fmaf(K[n], c[n], s);
        r = U_ * RCP(s);
        float q[8];
        #pragma unroll
        for (int n = 0; n < 8; ++n) q[n] = K[n] * r;
        q[0] += __shfl_xor(q[4], 8); q[1] += __shfl_xor(q[5], 8);
        q[2] += __shfl_xor(q[6], 8); q[3] += __shfl_xor(q[7], 8);
        q[0] += __shfl_xor(q[2], 4); q[1] += __shfl_xor(q[3], 4);
        q[0] += __shfl_xor(q[1], 2);
        q[0] += __shfl_xor(q[0], 1);
        c[0] = V_ * RCP(q[0]);
        c[1] = __shfl_xor(c[0], 2);
        c[2] = __shfl_xor(c[0], 4); c[3] = __shfl_xor(c[1], 4);
        c[4] = __shfl_xor(c[0], 8); c[5] = __shfl_xor(c[1], 8);
        c[6] = __shfl_xor(c[2], 8); c[7] = __shfl_xor(c[3], 8);
    }
    float g = 0.f;
    #pragma unroll
    for (int n = 0; n < 8; ++n) g = fmaf(K[n] * c[n], sv[n], g);
    float part = r * g;
    part += __shfl_xor(part, 1); part += __shfl_xor(part, 2);
    part += __shfl_xor(part, 4); part += __shfl_xor(part, 8);
    if (t == 0) score[p] = part;
}

// ---------------- final combine ----------------
__global__ __launch_bounds__(256)
void finalize_k(const float* __restrict__ st, const float* __restrict__ ss,
                const float* __restrict__ lsc, float* __restrict__ out)
{
    int i = blockIdx.x * 256 + threadIdx.x;
    float ls = __expf(lsc[0]);
    out[i] += 0.5f * ls * (st[i] + ss[i]);
}

extern "C" void kernel_launch(void* const* d_in, const int* in_sizes, int n_in,
                              void* d_out, int out_size, void* d_ws, size_t ws_size,
                              hipStream_t stream)
{
    (void)in_sizes; (void)n_in; (void)out_size; (void)ws_size;
    const float* imf = (const float*)d_in[0];
    const float* ds  = (const float*)d_in[1];   // spatial
    const float* dt  = (const float*)d_in[2];   // temporal
    const float* lsc = (const float*)d_in[3];
    float* out = (float*)d_out;

    float* imf_n    = (float*)d_ws;             // 2,097,152
    float* dsn      = imf_n + 2097152;          // 1,638,400
    float* dtn      = dsn + 1638400;            // 1,638,400
    float* img_pool = dtn + 1638400;            // 131,072
    float* dsum     = img_pool + 131072;        // 204,800
    float* sim      = dsum + 204800;            // 13,107,200
    float* errs     = sim + 13107200;           // 640,000
    float* err_iter = errs + 640000;            // 128
    float* ckc      = err_iter + 128;           // 4,915,200
    float* ckr      = ckc + 4915200;            // 3,276,800
    float* score_t  = ckr + 3276800;            // 102,400
    float* score_s  = score_t + 102400;         // 102,400
    int*   ifound   = (int*)(score_s + 102400); // found[2], iters[2]
    u16*   Ahi      = (u16*)(ifound + 4);       // 2,097,152 u16
    u16*   Alo      = Ahi + 2097152;
    u16*   Bshi     = Alo + 2097152;            // 1,638,400 u16 each
    u16*   Bslo     = Bshi + 1638400;
    u16*   Bthi     = Bslo + 1638400;
    u16*   Btlo     = Bthi + 1638400;

    norm_k<<<1024, 256, 0, stream>>>(imf, imf_n, Ahi, Alo, 4096);
    norm_k<<<800, 256, 0, stream>>>(ds, dsn, Bshi, Bslo, 3200);
    norm_k<<<800, 256, 0, stream>>>(dt, dtn, Bthi, Btlo, 3200);
    pools_k<<<1312, 256, 0, stream>>>(imf_n, dsn, dtn, img_pool, dsum, ifound);
    base_k<<<3200, 256, 0, stream>>>(img_pool, dsum, lsc, out);

    for (int set = 0; set < 2; ++set) {
        const u16* Bh = (set == 0) ? Bthi : Bshi;   // temporal first
        const u16* Bl = (set == 0) ? Btlo : Bslo;
        float* score = (set == 0) ? score_t : score_s;
        int* fnd = ifound + set;
        int* itr = ifound + 2 + set;
        gemm_mfma<<<800, 256, 0, stream>>>(Ahi, Alo, Bh, Bl, sim);
        sink_stage<<<6400, 256, 0, stream>>>(sim, errs, ckc, ckr, fnd, 0, 16);
        red_k<<<16, 256, 0, stream>>>(errs, err_iter, fnd, 0);
        fin_k<<<1, 64, 0, stream>>>(err_iter, itr, fnd, 0, 16, 0);
        sink_stage<<<6400, 256, 0, stream>>>(sim, errs, ckc, ckr, fnd, 16, 48);
        red_k<<<32, 256, 0, stream>>>(errs, err_iter, fnd, 16);
        fin_k<<<1, 64, 0, stream>>>(err_iter, itr, fnd, 16, 48, 0);
        sink_stage<<<6400, 256, 0, stream>>>(sim, errs, ckc, ckr, fnd, 48, 100);
        red_k<<<52, 256, 0, stream>>>(errs, err_iter, fnd, 48);
        fin_k<<<1, 64, 0, stream>>>(err_iter, itr, fnd, 48, 100, 1);
        sink_final<<<6400, 256, 0, stream>>>(sim, ckc, itr, score);
    }

    finalize_k<<<400, 256, 0, stream>>>(score_t, score_s, lsc, out);
}